// Round 20
// baseline (114.209 us; speedup 1.0000x reference)
//
#include <hip/hip_runtime.h>
#include <math.h>

#define BB 8
#define CC 320
#define ZB 2618880     // per-tensor bf16 z elems, levels 0..9
#define TTOT 4088      // pooled t elems, levels 1..9
#define NROWS 8184     // instance rows, levels 0..9
#define NROWS_T 16352  // temporal rows, levels 0..8
#define NTBLK 440      // symmetric temporal tiles
#define NP1 327680     // pool: level0-3 z items
#define NP2 5120       // pool tail: level4-9 columns (2*8*320)
#define NMRB 64        // merge_reduce blocks

// float offsets inside ws
#define FT 2618880
#define FPART 2622968
#define FCROSS 2799032
#define FROW 2807208   // per-row losses (NROWS floats, topk only)
#define FBLK 2815396   // 64 block partials
#define FCNT 2815460   // int counter

constexpr int kT[10]       = {512,256,128,64,32,16,8,4,2,1};
constexpr int kLogT[10]    = {9,8,7,6,5,4,3,2,1,0};
constexpr int kZBoff[10]   = {0,1310720,1966080,2293760,2457600,2539520,2580480,2600960,2611200,2616320};
constexpr int kToff[10]    = {0,0,2048,3072,3584,3840,3968,4032,4064,4080};
constexpr int kRowcum[11]  = {0,4096,6144,7168,7680,7936,8064,8128,8160,8176,8184};
constexpr int kTRowcum[10] = {0,8192,12288,14336,15360,15872,16128,16256,16320,16352};
constexpr int kNt128[9]    = {8,4,2,1,1,1,1,1,1};
constexpr int kLog128[9]   = {3,2,1,0,0,0,0,0,0};
constexpr int kPoff128[9]  = {0,65536,81920,86016,87040,87552,87808,87936,88000};
constexpr int kSblkcum[10] = {0,288,368,392,400,408,416,424,432,440};
constexpr int kXoff[9]     = {0,4096,6144,7168,7680,7936,8064,8128,8160};

typedef short v8s __attribute__((ext_vector_type(8)));
typedef float v16f __attribute__((ext_vector_type(16)));

__device__ __forceinline__ unsigned short f2bf(float x) {
    unsigned int u = __float_as_uint(x);
    u = (u + 0x7FFFu + ((u >> 16) & 1u)) >> 16;
    return (unsigned short)u;
}
__device__ __forceinline__ float bfu(unsigned short u) {
    return __uint_as_float(((unsigned int)u) << 16);
}

// ---------------------------------------------------------------------------
// D1: z levels 0-3 (+bf16 convert) + fp32 t-pool + z levels 4-9 directly
// from fp32 level 0 (round∘max == max∘round by monotonicity, so this is
// bit-identical to the former bf16 cascade) + counter init. The 4-9 tail is
// independent of all other work in this dispatch -> no barrier needed.
// ---------------------------------------------------------------------------
__global__ void pool_kernel(const float* __restrict__ z1,
                            const float* __restrict__ z2,
                            const float* __restrict__ t,
                            unsigned short* __restrict__ zb,
                            float* __restrict__ tpool,
                            int* __restrict__ counter) {
    int gid = blockIdx.x * 256 + threadIdx.x;
    if (gid == 0) *counter = 0;
    if (gid < NP1) {
        int c = gid % CC;
        int rest = gid / CC;
        int ch = rest & 63;
        int b = (rest >> 6) & 7;
        int which = rest >> 9;
        const float* src =
            (which ? z2 : z1) + ((size_t)(b * 512 + ch * 8)) * CC + c;
        unsigned short* dst = zb + (size_t)which * ZB;
        float v[8];
#pragma unroll
        for (int j = 0; j < 8; j++) v[j] = src[(size_t)j * CC];
#pragma unroll
        for (int j = 0; j < 8; j++)
            dst[(size_t)(b * 512 + ch * 8 + j) * CC + c] = f2bf(v[j]);
        float m1[4];
#pragma unroll
        for (int j = 0; j < 4; j++) m1[j] = fmaxf(v[2 * j], v[2 * j + 1]);
#pragma unroll
        for (int j = 0; j < 4; j++)
            dst[kZBoff[1] + (size_t)(b * 256 + ch * 4 + j) * CC + c] =
                f2bf(m1[j]);
        float m2[2] = {fmaxf(m1[0], m1[1]), fmaxf(m1[2], m1[3])};
#pragma unroll
        for (int j = 0; j < 2; j++)
            dst[kZBoff[2] + (size_t)(b * 128 + ch * 2 + j) * CC + c] =
                f2bf(m2[j]);
        dst[kZBoff[3] + (size_t)(b * 64 + ch) * CC + c] =
            f2bf(fmaxf(m2[0], m2[1]));
    } else if (gid < NP1 + TTOT) {
        int i = gid - NP1;
        int l = 1;
#pragma unroll
        for (int q = 2; q <= 9; q++) l = (i >= kToff[q]) ? q : l;
        int rem = i - kToff[l];
        int Tl = kT[l];
        int t2 = rem & (Tl - 1);
        int b = rem >> kLogT[l];
        int win = 512 / Tl;
        const float* p = t + b * 512 + t2 * win;
        float s = 0.f;
        for (int j = 0; j < win; j++) s += p[j];
        tpool[kToff[l] + rem] = s * (1.0f / win);
    } else if (gid < NP1 + TTOT + NP2) {
        int i = gid - (NP1 + TTOT);
        int c = i % CC;
        int r2 = i / CC;
        int b = r2 & 7;
        int which = r2 >> 3;
        const float* src = (which ? z2 : z1) + (size_t)(b * 512) * CC + c;
        unsigned short* base = zb + (size_t)which * ZB;
        float a[32];
        for (int g = 0; g < 32; g++) {
            float m = src[(size_t)(g * 16) * CC];
#pragma unroll
            for (int r = 1; r < 16; r++)
                m = fmaxf(m, src[(size_t)(g * 16 + r) * CC]);
            a[g] = m;
        }
#pragma unroll
        for (int j = 0; j < 32; j++)
            base[kZBoff[4] + (size_t)(b * 32 + j) * CC + c] = f2bf(a[j]);
#pragma unroll
        for (int j = 0; j < 16; j++) a[j] = fmaxf(a[2 * j], a[2 * j + 1]);
#pragma unroll
        for (int j = 0; j < 16; j++)
            base[kZBoff[5] + (size_t)(b * 16 + j) * CC + c] = f2bf(a[j]);
#pragma unroll
        for (int j = 0; j < 8; j++) a[j] = fmaxf(a[2 * j], a[2 * j + 1]);
#pragma unroll
        for (int j = 0; j < 8; j++)
            base[kZBoff[6] + (size_t)(b * 8 + j) * CC + c] = f2bf(a[j]);
#pragma unroll
        for (int j = 0; j < 4; j++) a[j] = fmaxf(a[2 * j], a[2 * j + 1]);
#pragma unroll
        for (int j = 0; j < 4; j++)
            base[kZBoff[7] + (size_t)(b * 4 + j) * CC + c] = f2bf(a[j]);
#pragma unroll
        for (int j = 0; j < 2; j++) a[j] = fmaxf(a[2 * j], a[2 * j + 1]);
#pragma unroll
        for (int j = 0; j < 2; j++)
            base[kZBoff[8] + (size_t)(b * 2 + j) * CC + c] = f2bf(a[j]);
        base[kZBoff[9] + (size_t)b * CC + c] = f2bf(fmaxf(a[0], a[1]));
    }
}

// ---------------------------------------------------------------------------
// D2: fused top-8 + instance loss, one wave per row.
// ---------------------------------------------------------------------------
__global__ void topk_kernel(const unsigned short* __restrict__ zb,
                            const float* __restrict__ t0,
                            const float* __restrict__ tpool,
                            float* __restrict__ rowloss) {
    int wave = threadIdx.x >> 6, lane = threadIdx.x & 63;
    int row = blockIdx.x * 4 + wave;
    if (row >= NROWS) return;
    int l = 0;
#pragma unroll
    for (int q = 1; q <= 9; q++) l = (row >= kRowcum[q]) ? q : l;
    int n = row - kRowcum[l];
    int T = kT[l];
    const float* tt = l ? tpool + kToff[l] : t0;
    int seq = n >> kLogT[l];
    float tn = tt[n];

    int idx8[8];
    if (lane < 8) {
        const float* ts = tt + lane * T;
        bool own = (lane == seq);
        int lo = 0, hi = T;
        while (lo < hi) {
            int mid = (lo + hi) >> 1;
            if (ts[mid] < tn) lo = mid + 1; else hi = mid;
        }
        int il = lo - 1, ih = lo;
        float dl = (il >= 0) ? (tn - ts[il]) : 3.0e38f;
        float dh = (ih < T) ? (ts[ih] - tn) : 3.0e38f;
#pragma unroll
        for (int r = 0; r < 8; r++) {
            bool pickLo = (dl <= dh);
            float dmin = own ? 1.0e12f : (pickLo ? dl : dh);
            int midx = own ? n : (lane * T + (pickLo ? il : ih));
            unsigned long long key =
                ((unsigned long long)__float_as_uint(dmin) << 32) |
                (unsigned int)midx;
            unsigned long long o;
            o = __shfl_xor(key, 1); key = (key < o) ? key : o;
            o = __shfl_xor(key, 2); key = (key < o) ? key : o;
            o = __shfl_xor(key, 4); key = (key < o) ? key : o;
            int widx = (int)(unsigned int)(key & 0xffffffffull);
            idx8[r] = widx;
            if (!own && widx == midx) {
                if (pickLo) { il--; dl = (il >= 0) ? (tn - ts[il]) : 3.0e38f; }
                else        { ih++; dh = (ih < T)  ? (ts[ih] - tn) : 3.0e38f; }
            }
        }
    }

    const unsigned short* z1 = zb + kZBoff[l];
    const unsigned short* z2 = zb + ZB + kZBoff[l];
    const unsigned short* z1n = z1 + (size_t)n * CC;
    const unsigned short* z2n = z2 + (size_t)n * CC;
    float a[5];
#pragma unroll
    for (int j = 0; j < 5; j++) a[j] = bfu(z1n[lane + 64 * j]);
    float part[17];
    {
        float s = 0.f;
#pragma unroll
        for (int j = 0; j < 5; j++) s += a[j] * bfu(z2n[lane + 64 * j]);
        part[0] = s;
    }
#pragma unroll
    for (int k = 0; k < 8; k++) {
        int p = __shfl(idx8[k], 0);
        const unsigned short* r1 = z1 + (size_t)p * CC;
        const unsigned short* r2 = z2 + (size_t)p * CC;
        float s1 = 0.f, s2 = 0.f;
#pragma unroll
        for (int j = 0; j < 5; j++) {
            float av = a[j];
            s1 += av * bfu(r1[lane + 64 * j]);
            s2 += av * bfu(r2[lane + 64 * j]);
        }
        part[1 + k] = s1;
        part[9 + k] = s2;
    }
#pragma unroll
    for (int q = 0; q < 17; q++) {
        float v = part[q];
        for (int off = 32; off > 0; off >>= 1) v += __shfl_xor(v, off);
        part[q] = v;
    }
    if (lane == 0) {
        float m = part[0];
#pragma unroll
        for (int q = 1; q < 17; q++) m = fmaxf(m, part[q]);
        float s = 0.f;
#pragma unroll
        for (int q = 0; q < 17; q++) s += expf(part[q] - m);
        float w = 0.05f / (float)(BB * T);
        rowloss[row] = w * (m + logf(s) - part[0]);
    }
}

// ---------------------------------------------------------------------------
// D3: symmetric temporal MFMA tiles, XCD-swizzled (batch -> XCD).
// ---------------------------------------------------------------------------
__global__ void __launch_bounds__(256) temporal_kernel(
        const unsigned short* __restrict__ zb, float2* __restrict__ part,
        float* __restrict__ crossbuf) {
    __shared__ __align__(16) char smem[16512];
    int bid = blockIdx.x, tid = threadIdx.x;
    int l = 0;
#pragma unroll
    for (int q = 1; q <= 8; q++) l = (bid >= kSblkcum[q]) ? q : l;
    int rem = bid - kSblkcum[l];
    int b = rem & 7;          // batch -> XCD (swizzle)
    int pr = rem >> 3;        // triangular tile index
    int Tl = kT[l], n = 2 * Tl, lnt = kLog128[l];
    int rt = 0, width = kNt128[l];
    while (pr >= width) { pr -= width; rt++; width--; }
    int ct = rt + pr;
    bool diag = (rt == ct);
    const unsigned short* zb1 = zb + kZBoff[l] + (size_t)b * Tl * CC;
    const unsigned short* zb2 = zb + ZB + kZBoff[l] + (size_t)b * Tl * CC;
    int row0 = rt * 128, col0 = ct * 128;
    int w = tid >> 6, lane = tid & 63;
    unsigned short* As = (unsigned short*)smem;
    unsigned short* Bs = (unsigned short*)(smem + 8192);
    float2* cred = (float2*)smem;  // overlays As after final k-loop barrier

    v16f acc[4];
#pragma unroll
    for (int cs = 0; cs < 4; cs++)
#pragma unroll
        for (int e = 0; e < 16; e++) acc[cs][e] = 0.f;

    int sofq[2]; const unsigned short* srcA[2]; const unsigned short* srcB[2];
    bool vA[2], vB[2];
#pragma unroll
    for (int q = 0; q < 2; q++) {
        int g = q * 256 + tid;
        int r = g & 127, kbb = g >> 7;
        sofq[q] = (r >> 5) * 1024 + (kbb >> 1) * 512 + (kbb & 1) * 256 +
                  (r & 31) * 8;
        int ka = kbb * 8;
        int gr = row0 + r;
        vA[q] = gr < n;
        srcA[q] = vA[q] ? ((gr < Tl) ? zb1 + (size_t)gr * CC + ka
                                     : zb2 + (size_t)(gr - Tl) * CC + ka)
                        : zb1;
        int gc = col0 + r;
        vB[q] = gc < n;
        srcB[q] = vB[q] ? ((gc < Tl) ? zb1 + (size_t)gc * CC + ka
                                     : zb2 + (size_t)(gc - Tl) * CC + ka)
                        : zb1;
    }

    for (int kc = 0; kc < CC; kc += 32) {
#pragma unroll
        for (int q = 0; q < 2; q++) {
            uint4 av = vA[q] ? *(const uint4*)(srcA[q] + kc)
                             : make_uint4(0, 0, 0, 0);
            *(uint4*)(As + sofq[q]) = av;
            if (!diag) {
                uint4 bv = vB[q] ? *(const uint4*)(srcB[q] + kc)
                                 : make_uint4(0, 0, 0, 0);
                *(uint4*)(Bs + sofq[q]) = bv;
            }
        }
        __syncthreads();
        const unsigned short* Ab = As + w * 1024;
        const unsigned short* Bb = diag ? As : Bs;
#pragma unroll
        for (int cc = 0; cc < 2; cc++) {
            v8s af = *(const v8s*)(Ab + cc * 512 + lane * 8);
#pragma unroll
            for (int cs = 0; cs < 4; cs++) {
                v8s bf = *(const v8s*)(Bb + cs * 1024 + cc * 512 + lane * 8);
                acc[cs] = __builtin_amdgcn_mfma_f32_32x32x16_bf16(
                    af, bf, acc[cs], 0, 0, 0);
            }
        }
        __syncthreads();
    }

    int colin = lane & 31;
    int rowhalf = 4 * (lane >> 5);

    // row pass
#pragma unroll
    for (int r = 0; r < 16; r++) {
        int lrow = (r & 3) + 8 * (r >> 2) + rowhalf;
        int grow = row0 + w * 32 + lrow;
        float vals[4];
        float lm = -3.0e38f;
#pragma unroll
        for (int cs = 0; cs < 4; cs++) {
            int gcol = col0 + cs * 32 + colin;
            float v = acc[cs][r];
            if (gcol >= n || gcol == grow) v = -3.0e38f;
            vals[cs] = v;
            lm = fmaxf(lm, v);
        }
#pragma unroll
        for (int off = 1; off < 32; off <<= 1)
            lm = fmaxf(lm, __shfl_xor(lm, off));
        float ls = 0.f;
#pragma unroll
        for (int cs = 0; cs < 4; cs++)
            ls += (vals[cs] > -1.0e38f) ? expf(vals[cs] - lm) : 0.f;
#pragma unroll
        for (int off = 1; off < 32; off <<= 1) ls += __shfl_xor(ls, off);
        if (colin == 0 && grow < n)
            part[kPoff128[l] + ((b * n + grow) << lnt) + ct] =
                make_float2(lm, ls);
    }

    // cross extraction
    if (ct - rt == (Tl >> 7)) {
#pragma unroll
        for (int r = 0; r < 16; r++) {
            int lrow = (r & 3) + 8 * (r >> 2) + rowhalf;
            int grow = row0 + w * 32 + lrow;
            if (grow < Tl) {
                int cidx = grow + Tl - col0;
                int cs_p = cidx >> 5, colin_p = cidx & 31;
                float cand = 0.f;
#pragma unroll
                for (int cs = 0; cs < 4; cs++)
                    cand += (cs == cs_p && colin == colin_p) ? acc[cs][r] : 0.f;
#pragma unroll
                for (int off = 1; off < 32; off <<= 1)
                    cand += __shfl_xor(cand, off);
                if (colin == 0)
                    crossbuf[kXoff[l] + b * Tl + grow] = cand;
            }
        }
    }

    // col pass (off-diagonal only)
    if (!diag) {
#pragma unroll
        for (int cs = 0; cs < 4; cs++) {
            float m = acc[cs][0];
#pragma unroll
            for (int r = 1; r < 16; r++) m = fmaxf(m, acc[cs][r]);
            float mo = __shfl_xor(m, 32);
            float mm = fmaxf(m, mo);
            float s = 0.f;
#pragma unroll
            for (int r = 0; r < 16; r++) s += expf(acc[cs][r] - mm);
            s += __shfl_xor(s, 32);
            if (lane < 32) cred[w * 128 + cs * 32 + lane] = make_float2(mm, s);
        }
    }
    __syncthreads();
    if (!diag && tid < 128) {
        float2 a0 = cred[0 * 128 + tid], a1 = cred[1 * 128 + tid];
        float2 a2 = cred[2 * 128 + tid], a3 = cred[3 * 128 + tid];
        float M = fmaxf(fmaxf(a0.x, a1.x), fmaxf(a2.x, a3.x));
        float S = a0.y * expf(a0.x - M) + a1.y * expf(a1.x - M) +
                  a2.y * expf(a2.x - M) + a3.y * expf(a3.x - M);
        int gcol = col0 + tid;
        part[kPoff128[l] + ((b * n + gcol) << lnt) + rt] = make_float2(M, S);
    }
}

// ---------------------------------------------------------------------------
__device__ __forceinline__ void d_merge_row(
        int row, const float2* __restrict__ part,
        const float* __restrict__ crossbuf, float* local) {
    int l = 0;
#pragma unroll
    for (int q = 1; q <= 8; q++) l = (row >= kTRowcum[q]) ? q : l;
    int r = row - kTRowcum[l];
    int Tl = kT[l], n = 2 * Tl, nt = kNt128[l], lnt = kLog128[l];
    int b = r >> (kLogT[l] + 1);
    int rr = r & (n - 1);
    const float2* p = part + kPoff128[l] + ((size_t)(b * n + rr) << lnt);
    float M = -3.0e38f, S = 0.f;
    for (int k = 0; k < nt; k++) {
        float2 q2 = p[k];
        float nM = fmaxf(M, q2.x);
        S = S * expf(M - nM) + q2.y * expf(q2.x - nM);
        M = nM;
    }
    float cross = crossbuf[kXoff[l] + b * Tl + (rr < Tl ? rr : rr - Tl)];
    float w = 0.025f / (float)(BB * Tl);
    *local += w * (M + logf(S) - cross);
}

// ---------------------------------------------------------------------------
// D4: merge temporal partials + sum topk rowloss + final reduce via the
// last-block pattern (device-scope atomics, fixed-order deterministic sum).
// ---------------------------------------------------------------------------
__global__ void merge_reduce_kernel(const float2* __restrict__ part,
                                    const float* __restrict__ crossbuf,
                                    const float* __restrict__ rowloss,
                                    float* __restrict__ blockpart,
                                    int* __restrict__ counter,
                                    float* __restrict__ out) {
    __shared__ float redsm[4];
    __shared__ int flag;
    int bid = blockIdx.x, tid = threadIdx.x;
    int gid = bid * 256 + tid;
    int wave = tid >> 6, lane = tid & 63;
    float local = 0.f;
    if (gid < NROWS_T) d_merge_row(gid, part, crossbuf, &local);
    if (gid < NROWS) local += rowloss[gid];
#pragma unroll
    for (int off = 32; off > 0; off >>= 1) local += __shfl_xor(local, off);
    if (lane == 0) redsm[wave] = local;
    __syncthreads();
    if (tid == 0) {
        float bs = redsm[0] + redsm[1] + redsm[2] + redsm[3];
        atomicExch(blockpart + bid, bs);
        __threadfence();
        int old = atomicAdd(counter, 1);
        flag = (old == NMRB - 1) ? 1 : 0;
    }
    __syncthreads();
    if (flag && tid < 64) {
        float v = atomicAdd(blockpart + tid, 0.0f);  // coherent read
#pragma unroll
        for (int off = 32; off > 0; off >>= 1) v += __shfl_xor(v, off);
        if (tid == 0) out[0] = v;
    }
}

extern "C" void kernel_launch(void* const* d_in, const int* in_sizes, int n_in,
                              void* d_out, int out_size, void* d_ws,
                              size_t ws_size, hipStream_t stream) {
    const float* z1 = (const float*)d_in[0];
    const float* z2 = (const float*)d_in[1];
    const float* t  = (const float*)d_in[2];
    float* ws = (float*)d_ws;
    unsigned short* zb = (unsigned short*)ws;
    float* tpool = ws + FT;
    float2* part = (float2*)(ws + FPART);
    float* crossbuf = ws + FCROSS;
    float* rowloss = ws + FROW;
    float* blockpart = ws + FBLK;
    int* counter = (int*)(ws + FCNT);
    float* out = (float*)d_out;

    pool_kernel<<<(NP1 + TTOT + NP2 + 255) / 256, 256, 0, stream>>>(
        z1, z2, t, zb, tpool, counter);
    topk_kernel<<<NROWS / 4, 256, 0, stream>>>(zb, t, tpool, rowloss);
    temporal_kernel<<<NTBLK, 256, 0, stream>>>(zb, part, crossbuf);
    merge_reduce_kernel<<<NMRB, 256, 0, stream>>>(part, crossbuf, rowloss,
                                                  blockpart, counter, out);
}

// Round 21
// 106.366 us; speedup vs baseline: 1.0737x; 1.0737x over previous
//
#include <hip/hip_runtime.h>
#include <math.h>

#define BB 8
#define CC 320
#define ZB 2618880     // per-tensor bf16 z elems, levels 0..9
#define TTOT 4088      // pooled t elems, levels 1..9
#define NROWS 8184     // instance rows, levels 0..9
#define NROWS_T 16352  // temporal rows, levels 0..8
#define NTBLK 440      // symmetric temporal tiles
#define NP1 327680     // pool: level0-3 z items
#define NP2 5120       // pool49 columns (2*8*320)
#define NMRB 64        // merge_reduce blocks

// float offsets inside ws
#define FT 2618880
#define FPART 2622968
#define FCROSS 2799032
#define FROW 2807208   // per-row losses (NROWS floats, topk only)
#define FBLK 2815396   // 64 block partials
#define FCNT 2815460   // int counter

constexpr int kT[10]       = {512,256,128,64,32,16,8,4,2,1};
constexpr int kLogT[10]    = {9,8,7,6,5,4,3,2,1,0};
constexpr int kZBoff[10]   = {0,1310720,1966080,2293760,2457600,2539520,2580480,2600960,2611200,2616320};
constexpr int kToff[10]    = {0,0,2048,3072,3584,3840,3968,4032,4064,4080};
constexpr int kRowcum[11]  = {0,4096,6144,7168,7680,7936,8064,8128,8160,8176,8184};
constexpr int kTRowcum[10] = {0,8192,12288,14336,15360,15872,16128,16256,16320,16352};
constexpr int kNt128[9]    = {8,4,2,1,1,1,1,1,1};
constexpr int kLog128[9]   = {3,2,1,0,0,0,0,0,0};
constexpr int kPoff128[9]  = {0,65536,81920,86016,87040,87552,87808,87936,88000};
constexpr int kSblkcum[10] = {0,288,368,392,400,408,416,424,432,440};
constexpr int kXoff[9]     = {0,4096,6144,7168,7680,7936,8064,8128,8160};

typedef short v8s __attribute__((ext_vector_type(8)));
typedef float v16f __attribute__((ext_vector_type(16)));

__device__ __forceinline__ unsigned short f2bf(float x) {
    unsigned int u = __float_as_uint(x);
    u = (u + 0x7FFFu + ((u >> 16) & 1u)) >> 16;
    return (unsigned short)u;
}
__device__ __forceinline__ float bfu(unsigned short u) {
    return __uint_as_float(((unsigned int)u) << 16);
}

// ---------------------------------------------------------------------------
// D1: level0-3 z pool (+bf16 convert) + fp32 t-pool + counter init.
// ---------------------------------------------------------------------------
__global__ void pool03_kernel(const float* __restrict__ z1,
                              const float* __restrict__ z2,
                              const float* __restrict__ t,
                              unsigned short* __restrict__ zb,
                              float* __restrict__ tpool,
                              int* __restrict__ counter) {
    int gid = blockIdx.x * 256 + threadIdx.x;
    if (gid == 0) *counter = 0;
    if (gid < NP1) {
        int c = gid % CC;
        int rest = gid / CC;
        int ch = rest & 63;
        int b = (rest >> 6) & 7;
        int which = rest >> 9;
        const float* src =
            (which ? z2 : z1) + ((size_t)(b * 512 + ch * 8)) * CC + c;
        unsigned short* dst = zb + (size_t)which * ZB;
        float v[8];
#pragma unroll
        for (int j = 0; j < 8; j++) v[j] = src[(size_t)j * CC];
#pragma unroll
        for (int j = 0; j < 8; j++)
            dst[(size_t)(b * 512 + ch * 8 + j) * CC + c] = f2bf(v[j]);
        float m1[4];
#pragma unroll
        for (int j = 0; j < 4; j++) m1[j] = fmaxf(v[2 * j], v[2 * j + 1]);
#pragma unroll
        for (int j = 0; j < 4; j++)
            dst[kZBoff[1] + (size_t)(b * 256 + ch * 4 + j) * CC + c] =
                f2bf(m1[j]);
        float m2[2] = {fmaxf(m1[0], m1[1]), fmaxf(m1[2], m1[3])};
#pragma unroll
        for (int j = 0; j < 2; j++)
            dst[kZBoff[2] + (size_t)(b * 128 + ch * 2 + j) * CC + c] =
                f2bf(m2[j]);
        dst[kZBoff[3] + (size_t)(b * 64 + ch) * CC + c] =
            f2bf(fmaxf(m2[0], m2[1]));
    } else if (gid < NP1 + TTOT) {
        int i = gid - NP1;
        int l = 1;
#pragma unroll
        for (int q = 2; q <= 9; q++) l = (i >= kToff[q]) ? q : l;
        int rem = i - kToff[l];
        int Tl = kT[l];
        int t2 = rem & (Tl - 1);
        int b = rem >> kLogT[l];
        int win = 512 / Tl;
        const float* p = t + b * 512 + t2 * win;
        float s = 0.f;
        for (int j = 0; j < win; j++) s += p[j];
        tpool[kToff[l] + rem] = s * (1.0f / win);
    }
}

// ---------------------------------------------------------------------------
// D2: bf16 max-pool levels 4..9 from level 3 (bit-identical cascade).
// ---------------------------------------------------------------------------
__global__ void pool49_kernel(unsigned short* __restrict__ zb) {
    int gid = blockIdx.x * 256 + threadIdx.x;
    if (gid >= NP2) return;
    int c = gid % CC;
    int r2 = gid / CC;
    int b = r2 & 7;
    int which = r2 >> 3;
    unsigned short* base = zb + (size_t)which * ZB;
    const unsigned short* src = base + kZBoff[3] + (size_t)(b * 64) * CC + c;
    float a[32];
#pragma unroll
    for (int j = 0; j < 32; j++)
        a[j] = fmaxf(bfu(src[(size_t)(2 * j) * CC]),
                     bfu(src[(size_t)(2 * j + 1) * CC]));
#pragma unroll
    for (int j = 0; j < 32; j++)
        base[kZBoff[4] + (size_t)(b * 32 + j) * CC + c] = f2bf(a[j]);
#pragma unroll
    for (int j = 0; j < 16; j++) a[j] = fmaxf(a[2 * j], a[2 * j + 1]);
#pragma unroll
    for (int j = 0; j < 16; j++)
        base[kZBoff[5] + (size_t)(b * 16 + j) * CC + c] = f2bf(a[j]);
#pragma unroll
    for (int j = 0; j < 8; j++) a[j] = fmaxf(a[2 * j], a[2 * j + 1]);
#pragma unroll
    for (int j = 0; j < 8; j++)
        base[kZBoff[6] + (size_t)(b * 8 + j) * CC + c] = f2bf(a[j]);
#pragma unroll
    for (int j = 0; j < 4; j++) a[j] = fmaxf(a[2 * j], a[2 * j + 1]);
#pragma unroll
    for (int j = 0; j < 4; j++)
        base[kZBoff[7] + (size_t)(b * 4 + j) * CC + c] = f2bf(a[j]);
#pragma unroll
    for (int j = 0; j < 2; j++) a[j] = fmaxf(a[2 * j], a[2 * j + 1]);
#pragma unroll
    for (int j = 0; j < 2; j++)
        base[kZBoff[8] + (size_t)(b * 2 + j) * CC + c] = f2bf(a[j]);
    base[kZBoff[9] + (size_t)b * CC + c] = f2bf(fmaxf(a[0], a[1]));
}

// ---------------------------------------------------------------------------
// D3: fused top-8 + instance loss, one wave per row.
// ---------------------------------------------------------------------------
__global__ void topk_kernel(const unsigned short* __restrict__ zb,
                            const float* __restrict__ t0,
                            const float* __restrict__ tpool,
                            float* __restrict__ rowloss) {
    int wave = threadIdx.x >> 6, lane = threadIdx.x & 63;
    int row = blockIdx.x * 4 + wave;
    if (row >= NROWS) return;
    int l = 0;
#pragma unroll
    for (int q = 1; q <= 9; q++) l = (row >= kRowcum[q]) ? q : l;
    int n = row - kRowcum[l];
    int T = kT[l];
    const float* tt = l ? tpool + kToff[l] : t0;
    int seq = n >> kLogT[l];
    float tn = tt[n];

    int idx8[8];
    if (lane < 8) {
        const float* ts = tt + lane * T;
        bool own = (lane == seq);
        int lo = 0, hi = T;
        while (lo < hi) {
            int mid = (lo + hi) >> 1;
            if (ts[mid] < tn) lo = mid + 1; else hi = mid;
        }
        int il = lo - 1, ih = lo;
        float dl = (il >= 0) ? (tn - ts[il]) : 3.0e38f;
        float dh = (ih < T) ? (ts[ih] - tn) : 3.0e38f;
#pragma unroll
        for (int r = 0; r < 8; r++) {
            bool pickLo = (dl <= dh);
            float dmin = own ? 1.0e12f : (pickLo ? dl : dh);
            int midx = own ? n : (lane * T + (pickLo ? il : ih));
            unsigned long long key =
                ((unsigned long long)__float_as_uint(dmin) << 32) |
                (unsigned int)midx;
            unsigned long long o;
            o = __shfl_xor(key, 1); key = (key < o) ? key : o;
            o = __shfl_xor(key, 2); key = (key < o) ? key : o;
            o = __shfl_xor(key, 4); key = (key < o) ? key : o;
            int widx = (int)(unsigned int)(key & 0xffffffffull);
            idx8[r] = widx;
            if (!own && widx == midx) {
                if (pickLo) { il--; dl = (il >= 0) ? (tn - ts[il]) : 3.0e38f; }
                else        { ih++; dh = (ih < T)  ? (ts[ih] - tn) : 3.0e38f; }
            }
        }
    }

    const unsigned short* z1 = zb + kZBoff[l];
    const unsigned short* z2 = zb + ZB + kZBoff[l];
    const unsigned short* z1n = z1 + (size_t)n * CC;
    const unsigned short* z2n = z2 + (size_t)n * CC;
    float a[5];
#pragma unroll
    for (int j = 0; j < 5; j++) a[j] = bfu(z1n[lane + 64 * j]);
    float part[17];
    {
        float s = 0.f;
#pragma unroll
        for (int j = 0; j < 5; j++) s += a[j] * bfu(z2n[lane + 64 * j]);
        part[0] = s;
    }
#pragma unroll
    for (int k = 0; k < 8; k++) {
        int p = __shfl(idx8[k], 0);
        const unsigned short* r1 = z1 + (size_t)p * CC;
        const unsigned short* r2 = z2 + (size_t)p * CC;
        float s1 = 0.f, s2 = 0.f;
#pragma unroll
        for (int j = 0; j < 5; j++) {
            float av = a[j];
            s1 += av * bfu(r1[lane + 64 * j]);
            s2 += av * bfu(r2[lane + 64 * j]);
        }
        part[1 + k] = s1;
        part[9 + k] = s2;
    }
#pragma unroll
    for (int q = 0; q < 17; q++) {
        float v = part[q];
        for (int off = 32; off > 0; off >>= 1) v += __shfl_xor(v, off);
        part[q] = v;
    }
    if (lane == 0) {
        float m = part[0];
#pragma unroll
        for (int q = 1; q < 17; q++) m = fmaxf(m, part[q]);
        float s = 0.f;
#pragma unroll
        for (int q = 0; q < 17; q++) s += expf(part[q] - m);
        float w = 0.05f / (float)(BB * T);
        rowloss[row] = w * (m + logf(s) - part[0]);
    }
}

// ---------------------------------------------------------------------------
// D4: symmetric temporal MFMA tiles, XCD-swizzled (batch -> XCD).
// ---------------------------------------------------------------------------
__global__ void __launch_bounds__(256) temporal_kernel(
        const unsigned short* __restrict__ zb, float2* __restrict__ part,
        float* __restrict__ crossbuf) {
    __shared__ __align__(16) char smem[16512];
    int bid = blockIdx.x, tid = threadIdx.x;
    int l = 0;
#pragma unroll
    for (int q = 1; q <= 8; q++) l = (bid >= kSblkcum[q]) ? q : l;
    int rem = bid - kSblkcum[l];
    int b = rem & 7;          // batch -> XCD (swizzle)
    int pr = rem >> 3;        // triangular tile index
    int Tl = kT[l], n = 2 * Tl, lnt = kLog128[l];
    int rt = 0, width = kNt128[l];
    while (pr >= width) { pr -= width; rt++; width--; }
    int ct = rt + pr;
    bool diag = (rt == ct);
    const unsigned short* zb1 = zb + kZBoff[l] + (size_t)b * Tl * CC;
    const unsigned short* zb2 = zb + ZB + kZBoff[l] + (size_t)b * Tl * CC;
    int row0 = rt * 128, col0 = ct * 128;
    int w = tid >> 6, lane = tid & 63;
    unsigned short* As = (unsigned short*)smem;
    unsigned short* Bs = (unsigned short*)(smem + 8192);
    float2* cred = (float2*)smem;  // overlays As after final k-loop barrier

    v16f acc[4];
#pragma unroll
    for (int cs = 0; cs < 4; cs++)
#pragma unroll
        for (int e = 0; e < 16; e++) acc[cs][e] = 0.f;

    int sofq[2]; const unsigned short* srcA[2]; const unsigned short* srcB[2];
    bool vA[2], vB[2];
#pragma unroll
    for (int q = 0; q < 2; q++) {
        int g = q * 256 + tid;
        int r = g & 127, kbb = g >> 7;
        sofq[q] = (r >> 5) * 1024 + (kbb >> 1) * 512 + (kbb & 1) * 256 +
                  (r & 31) * 8;
        int ka = kbb * 8;
        int gr = row0 + r;
        vA[q] = gr < n;
        srcA[q] = vA[q] ? ((gr < Tl) ? zb1 + (size_t)gr * CC + ka
                                     : zb2 + (size_t)(gr - Tl) * CC + ka)
                        : zb1;
        int gc = col0 + r;
        vB[q] = gc < n;
        srcB[q] = vB[q] ? ((gc < Tl) ? zb1 + (size_t)gc * CC + ka
                                     : zb2 + (size_t)(gc - Tl) * CC + ka)
                        : zb1;
    }

    for (int kc = 0; kc < CC; kc += 32) {
#pragma unroll
        for (int q = 0; q < 2; q++) {
            uint4 av = vA[q] ? *(const uint4*)(srcA[q] + kc)
                             : make_uint4(0, 0, 0, 0);
            *(uint4*)(As + sofq[q]) = av;
            if (!diag) {
                uint4 bv = vB[q] ? *(const uint4*)(srcB[q] + kc)
                                 : make_uint4(0, 0, 0, 0);
                *(uint4*)(Bs + sofq[q]) = bv;
            }
        }
        __syncthreads();
        const unsigned short* Ab = As + w * 1024;
        const unsigned short* Bb = diag ? As : Bs;
#pragma unroll
        for (int cc = 0; cc < 2; cc++) {
            v8s af = *(const v8s*)(Ab + cc * 512 + lane * 8);
#pragma unroll
            for (int cs = 0; cs < 4; cs++) {
                v8s bf = *(const v8s*)(Bb + cs * 1024 + cc * 512 + lane * 8);
                acc[cs] = __builtin_amdgcn_mfma_f32_32x32x16_bf16(
                    af, bf, acc[cs], 0, 0, 0);
            }
        }
        __syncthreads();
    }

    int colin = lane & 31;
    int rowhalf = 4 * (lane >> 5);

    // row pass
#pragma unroll
    for (int r = 0; r < 16; r++) {
        int lrow = (r & 3) + 8 * (r >> 2) + rowhalf;
        int grow = row0 + w * 32 + lrow;
        float vals[4];
        float lm = -3.0e38f;
#pragma unroll
        for (int cs = 0; cs < 4; cs++) {
            int gcol = col0 + cs * 32 + colin;
            float v = acc[cs][r];
            if (gcol >= n || gcol == grow) v = -3.0e38f;
            vals[cs] = v;
            lm = fmaxf(lm, v);
        }
#pragma unroll
        for (int off = 1; off < 32; off <<= 1)
            lm = fmaxf(lm, __shfl_xor(lm, off));
        float ls = 0.f;
#pragma unroll
        for (int cs = 0; cs < 4; cs++)
            ls += (vals[cs] > -1.0e38f) ? expf(vals[cs] - lm) : 0.f;
#pragma unroll
        for (int off = 1; off < 32; off <<= 1) ls += __shfl_xor(ls, off);
        if (colin == 0 && grow < n)
            part[kPoff128[l] + ((b * n + grow) << lnt) + ct] =
                make_float2(lm, ls);
    }

    // cross extraction
    if (ct - rt == (Tl >> 7)) {
#pragma unroll
        for (int r = 0; r < 16; r++) {
            int lrow = (r & 3) + 8 * (r >> 2) + rowhalf;
            int grow = row0 + w * 32 + lrow;
            if (grow < Tl) {
                int cidx = grow + Tl - col0;
                int cs_p = cidx >> 5, colin_p = cidx & 31;
                float cand = 0.f;
#pragma unroll
                for (int cs = 0; cs < 4; cs++)
                    cand += (cs == cs_p && colin == colin_p) ? acc[cs][r] : 0.f;
#pragma unroll
                for (int off = 1; off < 32; off <<= 1)
                    cand += __shfl_xor(cand, off);
                if (colin == 0)
                    crossbuf[kXoff[l] + b * Tl + grow] = cand;
            }
        }
    }

    // col pass (off-diagonal only)
    if (!diag) {
#pragma unroll
        for (int cs = 0; cs < 4; cs++) {
            float m = acc[cs][0];
#pragma unroll
            for (int r = 1; r < 16; r++) m = fmaxf(m, acc[cs][r]);
            float mo = __shfl_xor(m, 32);
            float mm = fmaxf(m, mo);
            float s = 0.f;
#pragma unroll
            for (int r = 0; r < 16; r++) s += expf(acc[cs][r] - mm);
            s += __shfl_xor(s, 32);
            if (lane < 32) cred[w * 128 + cs * 32 + lane] = make_float2(mm, s);
        }
    }
    __syncthreads();
    if (!diag && tid < 128) {
        float2 a0 = cred[0 * 128 + tid], a1 = cred[1 * 128 + tid];
        float2 a2 = cred[2 * 128 + tid], a3 = cred[3 * 128 + tid];
        float M = fmaxf(fmaxf(a0.x, a1.x), fmaxf(a2.x, a3.x));
        float S = a0.y * expf(a0.x - M) + a1.y * expf(a1.x - M) +
                  a2.y * expf(a2.x - M) + a3.y * expf(a3.x - M);
        int gcol = col0 + tid;
        part[kPoff128[l] + ((b * n + gcol) << lnt) + rt] = make_float2(M, S);
    }
}

// ---------------------------------------------------------------------------
__device__ __forceinline__ void d_merge_row(
        int row, const float2* __restrict__ part,
        const float* __restrict__ crossbuf, float* local) {
    int l = 0;
#pragma unroll
    for (int q = 1; q <= 8; q++) l = (row >= kTRowcum[q]) ? q : l;
    int r = row - kTRowcum[l];
    int Tl = kT[l], n = 2 * Tl, nt = kNt128[l], lnt = kLog128[l];
    int b = r >> (kLogT[l] + 1);
    int rr = r & (n - 1);
    const float2* p = part + kPoff128[l] + ((size_t)(b * n + rr) << lnt);
    float M = -3.0e38f, S = 0.f;
    for (int k = 0; k < nt; k++) {
        float2 q2 = p[k];
        float nM = fmaxf(M, q2.x);
        S = S * expf(M - nM) + q2.y * expf(q2.x - nM);
        M = nM;
    }
    float cross = crossbuf[kXoff[l] + b * Tl + (rr < Tl ? rr : rr - Tl)];
    float w = 0.025f / (float)(BB * Tl);
    *local += w * (M + logf(S) - cross);
}

// ---------------------------------------------------------------------------
// D5: merge temporal partials + sum topk rowloss + final reduce via the
// last-block pattern (device-scope atomics, fixed-order deterministic sum).
// ---------------------------------------------------------------------------
__global__ void merge_reduce_kernel(const float2* __restrict__ part,
                                    const float* __restrict__ crossbuf,
                                    const float* __restrict__ rowloss,
                                    float* __restrict__ blockpart,
                                    int* __restrict__ counter,
                                    float* __restrict__ out) {
    __shared__ float redsm[4];
    __shared__ int flag;
    int bid = blockIdx.x, tid = threadIdx.x;
    int gid = bid * 256 + tid;
    int wave = tid >> 6, lane = tid & 63;
    float local = 0.f;
    if (gid < NROWS_T) d_merge_row(gid, part, crossbuf, &local);
    if (gid < NROWS) local += rowloss[gid];
#pragma unroll
    for (int off = 32; off > 0; off >>= 1) local += __shfl_xor(local, off);
    if (lane == 0) redsm[wave] = local;
    __syncthreads();
    if (tid == 0) {
        float bs = redsm[0] + redsm[1] + redsm[2] + redsm[3];
        atomicExch(blockpart + bid, bs);
        __threadfence();
        int old = atomicAdd(counter, 1);
        flag = (old == NMRB - 1) ? 1 : 0;
    }
    __syncthreads();
    if (flag && tid < 64) {
        float v = atomicAdd(blockpart + tid, 0.0f);  // coherent read
#pragma unroll
        for (int off = 32; off > 0; off >>= 1) v += __shfl_xor(v, off);
        if (tid == 0) out[0] = v;
    }
}

extern "C" void kernel_launch(void* const* d_in, const int* in_sizes, int n_in,
                              void* d_out, int out_size, void* d_ws,
                              size_t ws_size, hipStream_t stream) {
    const float* z1 = (const float*)d_in[0];
    const float* z2 = (const float*)d_in[1];
    const float* t  = (const float*)d_in[2];
    float* ws = (float*)d_ws;
    unsigned short* zb = (unsigned short*)ws;
    float* tpool = ws + FT;
    float2* part = (float2*)(ws + FPART);
    float* crossbuf = ws + FCROSS;
    float* rowloss = ws + FROW;
    float* blockpart = ws + FBLK;
    int* counter = (int*)(ws + FCNT);
    float* out = (float*)d_out;

    pool03_kernel<<<(NP1 + TTOT + 255) / 256, 256, 0, stream>>>(
        z1, z2, t, zb, tpool, counter);
    pool49_kernel<<<(NP2 + 255) / 256, 256, 0, stream>>>(zb);
    topk_kernel<<<NROWS / 4, 256, 0, stream>>>(zb, t, tpool, rowloss);
    temporal_kernel<<<NTBLK, 256, 0, stream>>>(zb, part, crossbuf);
    merge_reduce_kernel<<<NMRB, 256, 0, stream>>>(part, crossbuf, rowloss,
                                                  blockpart, counter, out);
}